// Round 10
// baseline (172.158 us; speedup 1.0000x reference)
//
#include <hip/hip_runtime.h>
#include <hip/hip_bf16.h>
#include <stdint.h>

// Problem constants: B=2, M=8192, D=1024, H=16, hd=64, SEG=2048, DIL=8
// => S=4 segments, Kn=256 dilated keys/segment, nb=32 query blocks of 64.

typedef __attribute__((ext_vector_type(8))) short short8;
typedef __attribute__((ext_vector_type(4))) float f32x4;
typedef __attribute__((ext_vector_type(4))) unsigned short ushort4v;

#define DEVI static __device__ __forceinline__

DEVI unsigned short f2bf(float f) {
  union { float f; uint32_t u; } v; v.f = f;
  return (unsigned short)((v.u + 0x7FFFu + ((v.u >> 16) & 1u)) >> 16);
}

// Pure-C bf16 pair pack (v_cvt_pk_bf16_f32 inline asm was broken - round 4/5).
DEVI uint32_t pack_bf16(float lo, float hi) {
  return (uint32_t)f2bf(lo) | ((uint32_t)f2bf(hi) << 16);
}

DEVI void gload_lds16(const void* g, void* l) {
  __builtin_amdgcn_global_load_lds((const __attribute__((address_space(1))) void*)g,
                                   (__attribute__((address_space(3))) void*)l,
                                   16, 0, 0);
}

// ---------------- f32 -> bf16 convert ----------------
__global__ void cvt_kernel(const float* __restrict__ in, unsigned short* __restrict__ out, int n) {
  int i = (blockIdx.x * 256 + threadIdx.x) * 4;
  if (i >= n) return;
  float4 f = *(const float4*)(in + i);
  uint2 o;
  o.x = (uint32_t)f2bf(f.x) | ((uint32_t)f2bf(f.y) << 16);
  o.y = (uint32_t)f2bf(f.z) | ((uint32_t)f2bf(f.w) << 16);
  *(uint2*)(out + i) = o;
}

// ======== 8-phase 256x256 GEMM, gray-code reuse + thin counted vmcnt ========
// C[m,n] = scale * sum_k A[m,k]*B[n,k];  A [M][1024], B [1024][1024] bf16.
// 512 threads = 8 waves (2M x 4N); per-wave C = 128x64, rows/cols interleaved
// across tile halves; gray-code quadrant order (0,0)->(0,1)->(1,1)->(1,0):
// A-frags reload q=0,2 (8 reads), B-frags q=0,1,3 (4 reads).
// Phase rhythm (r8-proven): {ds_read; stage; BAR; lgkm0+schedbar; prio1 MFMA16
// prio0; [wait]; BAR}.  Stage spread (gray-code makes buf0 units dead early):
//   p0: buf1<-A0',B0' (tile 2t+1)   p1: buf1<-A1',B1'
//   p2: buf0<-A0 (tile 2t+2)  p3: buf0<-B1  p4: buf0<-B0  p5: buf0<-A1
// Waits ONLY 3x/iter (never drain to 0 until tail):
//   end-p1: vmcnt(8)  retires prev-iter A1 (needed by p2)
//   end-p3: vmcnt(4)  retires p0,p1 batches = all of buf1 (needed by p4-p7)
//           (t=7: vmcnt(0) since p2..p5 stages are skipped)
//   end-p7: vmcnt(2)  retires p2,p3,p4 = A0,B1,B0 (needed by next p0,p1)
// Per-unit retire/overwrite margins verified; loop exits with 0 outstanding.
#define STAGE_A(bf, hf, kt) do { \
  gload_lds16(Abase + (long)((hf) * 128 + srow0) * 1024 + (kt) * 64 + scol0, &smA[bf][hf][se0]); \
  gload_lds16(Abase + (long)((hf) * 128 + srow1) * 1024 + (kt) * 64 + scol1, &smA[bf][hf][se1]); \
} while (0)
#define STAGE_B(bf, hf, kt) do { \
  gload_lds16(Bbase + (long)((hf) * 128 + srow0) * 1024 + (kt) * 64 + scol0, &smB[bf][hf][se0]); \
  gload_lds16(Bbase + (long)((hf) * 128 + srow1) * 1024 + (kt) * 64 + scol1, &smB[bf][hf][se1]); \
} while (0)

template<bool OUT_F32>
__global__ __launch_bounds__(512, 1) void gemm8p(
    const unsigned short* __restrict__ A, const unsigned short* __restrict__ B,
    void* __restrict__ Cv, float scale)
{
  __shared__ unsigned short smA[2][2][128 * 64];   // [buf][half][r][k] swizzled
  __shared__ unsigned short smB[2][2][128 * 64];
  const int tid = threadIdx.x;
  const int tm = blockIdx.x, tn = blockIdx.y;
  const int w = tid >> 6, lane = tid & 63;
  const int wm = w >> 2, wn = w & 3;
  const int lr = lane & 15, lq = lane >> 4;

  // staging source precompute (2 x 16B per thread per 128x64 unit)
  const int e0 = tid * 8,        e1 = (512 + tid) * 8;
  const int srow0 = e0 >> 6,     srow1 = e1 >> 6;
  const int sc0 = (e0 >> 3) & 7, sc1 = (e1 >> 3) & 7;
  const int scol0 = (sc0 ^ (srow0 & 7)) * 8, scol1 = (sc1 ^ (srow1 & 7)) * 8;
  const int se0 = e0, se1 = e1;

  const unsigned short* Abase = A + (long)tm * 256 * 1024;
  const unsigned short* Bbase = B + (long)tn * 256 * 1024;

  f32x4 acc[8][4] = {};
  short8 af[4][2];   // current A-half fragments (persist 2 phases)
  short8 bfr[2][2];  // current B-half fragments

  // prologue: stage all of K-tile 0 into buf0, drain, sync
  STAGE_A(0, 0, 0); STAGE_B(0, 0, 0); STAGE_B(0, 1, 0); STAGE_A(0, 1, 0);
  asm volatile("s_waitcnt vmcnt(0)" ::: "memory");
  __builtin_amdgcn_s_barrier();
  asm volatile("" ::: "memory");

  for (int t = 0; t < 8; ++t) {
#pragma unroll
    for (int p = 0; p < 8; ++p) {
      const int o = p >> 2;            // LDS buf: 0 for kt=2t, 1 for kt=2t+1
      const int q = p & 3;
      const int a = (p >> 1) & 1;      // A-half: 0,0,1,1
      const int b = a ^ (q & 1);       // B-half: 0,1,1,0 (gray)

      // ---- ds_read only NEW fragments for THIS phase
      if ((q & 1) == 0) {              // q=0,2: new A-half (8 x b128)
#pragma unroll
        for (int mi2 = 0; mi2 < 4; ++mi2) {
          int r = wm * 64 + mi2 * 16 + lr;
#pragma unroll
          for (int kk = 0; kk < 2; ++kk) {
            int kc = kk * 4 + lq;
            af[mi2][kk] = *(const short8*)&smA[o][a][r * 64 + ((kc ^ (r & 7)) * 8)];
          }
        }
      }
      if (q != 2) {                    // q=0,1,3: new B-half (4 x b128)
#pragma unroll
        for (int nj2 = 0; nj2 < 2; ++nj2) {
          int r = wn * 32 + nj2 * 16 + lr;
#pragma unroll
          for (int kk = 0; kk < 2; ++kk) {
            int kc = kk * 4 + lq;
            bfr[nj2][kk] = *(const short8*)&smB[o][b][r * 64 + ((kc ^ (r & 7)) * 8)];
          }
        }
      }

      // ---- stage (spread schedule; see header)
      switch (p) {
        case 0: STAGE_A(1, 0, 2 * t + 1); STAGE_B(1, 0, 2 * t + 1); break;
        case 1: STAGE_A(1, 1, 2 * t + 1); STAGE_B(1, 1, 2 * t + 1); break;
        case 2: if (t < 7) STAGE_A(0, 0, 2 * t + 2); break;
        case 3: if (t < 7) STAGE_B(0, 1, 2 * t + 2); break;
        case 4: if (t < 7) STAGE_B(0, 0, 2 * t + 2); break;
        case 5: if (t < 7) STAGE_A(0, 1, 2 * t + 2); break;
      }

      // ---- mid barrier, drain ds_reads, MFMA cluster
      __builtin_amdgcn_s_barrier();
      asm volatile("s_waitcnt lgkmcnt(0)" ::: "memory");
      __builtin_amdgcn_sched_barrier(0);

      __builtin_amdgcn_s_setprio(1);
#pragma unroll
      for (int kk = 0; kk < 2; ++kk)
#pragma unroll
        for (int mi2 = 0; mi2 < 4; ++mi2)
#pragma unroll
          for (int nj2 = 0; nj2 < 2; ++nj2)
            acc[a * 4 + mi2][b * 2 + nj2] = __builtin_amdgcn_mfma_f32_16x16x32_bf16(
                af[mi2][kk], bfr[nj2][kk], acc[a * 4 + mi2][b * 2 + nj2], 0, 0, 0);
      __builtin_amdgcn_s_setprio(0);

      // ---- thin counted waits (3 per iteration)
      if (p == 1) {
        asm volatile("s_waitcnt vmcnt(8)" ::: "memory");
      } else if (p == 3) {
        if (t < 7) asm volatile("s_waitcnt vmcnt(4)" ::: "memory");
        else       asm volatile("s_waitcnt vmcnt(0)" ::: "memory");
      } else if (p == 7 && t < 7) {
        asm volatile("s_waitcnt vmcnt(2)" ::: "memory");
      }
      __builtin_amdgcn_s_barrier();
      asm volatile("" ::: "memory");
    }
  }

  // ---- epilogue
  const int row0 = tm * 256 + wm * 64 + lq * 4;
  const int col0 = tn * 256 + wn * 32 + lr;
#pragma unroll
  for (int mi = 0; mi < 8; ++mi) {
    int row = row0 + (mi & 3) * 16 + (mi >> 2) * 128;
#pragma unroll
    for (int nj = 0; nj < 4; ++nj) {
      int col = col0 + (nj & 1) * 16 + (nj >> 1) * 128;
#pragma unroll
      for (int rr = 0; rr < 4; ++rr) {
        float v = acc[mi][nj][rr] * scale;
        long off = (long)(row + rr) * 1024 + col;
        if (OUT_F32) ((float*)Cv)[off] = v;
        else         ((unsigned short*)Cv)[off] = f2bf(v);
      }
    }
  }
}

// ---------------- 128^2 GEMM, kept for the KV split ----------------
// EPI 2: tn<8 -> bf16 K rows to Cv; tn>=8 -> V TRANSPOSED + sigma-permuted to
// Cv2 (row = seg*1024+f; u32 col c packs tokens (32*(c>>4)+(c&15), +16)).
template<int EPI>
__global__ __launch_bounds__(256, 2) void gemm_bt(
    const unsigned short* __restrict__ A, const unsigned short* __restrict__ B,
    void* __restrict__ Cv, unsigned short* __restrict__ Cv2,
    float scale, long a_row_stride, int ldc, int K)
{
  __shared__ unsigned short smA[128 * 64];
  __shared__ unsigned short smB[128 * 64];
  const int tid = threadIdx.x;
  const int tm = blockIdx.x, tn = blockIdx.y;
  const int w = tid >> 6, lane = tid & 63;
  const int wr = (w >> 1) * 64, wc = (w & 1) * 64;
  const int lr = lane & 15, lq = lane >> 4;

  int se[4], srow[4], scol[4];
#pragma unroll
  for (int i = 0; i < 4; ++i) {
    int e = (i * 256 + tid) * 8;
    int r = e >> 6;
    int cc = (e >> 3) & 7;
    se[i] = e; srow[i] = r; scol[i] = (cc ^ (r & 7)) * 8;
  }

  f32x4 acc[4][4] = {};

  for (int kt = 0; kt < K / 64; ++kt) {
    if (kt) __syncthreads();
#pragma unroll
    for (int i = 0; i < 4; ++i)
      gload_lds16(A + (long)(tm * 128 + srow[i]) * a_row_stride + kt * 64 + scol[i], &smA[se[i]]);
#pragma unroll
    for (int i = 0; i < 4; ++i)
      gload_lds16(B + (long)(tn * 128 + srow[i]) * K + kt * 64 + scol[i], &smB[se[i]]);
    __syncthreads();

#pragma unroll
    for (int kk = 0; kk < 2; ++kk) {
      int kc = kk * 4 + lq;
      short8 af[4], bfm[4];
#pragma unroll
      for (int i = 0; i < 4; ++i) {
        int row = wr + i * 16 + lr;
        af[i] = *(const short8*)&smA[row * 64 + ((kc ^ (row & 7)) * 8)];
      }
#pragma unroll
      for (int j = 0; j < 4; ++j) {
        int row = wc + j * 16 + lr;
        bfm[j] = *(const short8*)&smB[row * 64 + ((kc ^ (row & 7)) * 8)];
      }
#pragma unroll
      for (int i = 0; i < 4; ++i)
#pragma unroll
        for (int j = 0; j < 4; ++j)
          acc[i][j] = __builtin_amdgcn_mfma_f32_16x16x32_bf16(af[i], bfm[j], acc[i][j], 0, 0, 0);
    }
  }

  if (EPI == 2 && tn >= 8) {
    const int fbase = (tn - 8) * 128 + wc;
#pragma unroll
    for (int ip = 0; ip < 4; ip += 2) {
      int t0 = tm * 128 + wr + ip * 16 + lq * 4;
      int seg = t0 >> 8;
      int ts  = t0 & 255;
      int c32 = (ts >> 5) * 16 + (ts & 15);
#pragma unroll
      for (int j = 0; j < 4; ++j) {
        int f = fbase + j * 16 + lr;
        uint32_t* rp = (uint32_t*)&Cv2[((long)(seg * 1024 + f)) * 256];
        uint4 U;
        U.x = pack_bf16(acc[ip][j][0] * scale, acc[ip + 1][j][0] * scale);
        U.y = pack_bf16(acc[ip][j][1] * scale, acc[ip + 1][j][1] * scale);
        U.z = pack_bf16(acc[ip][j][2] * scale, acc[ip + 1][j][2] * scale);
        U.w = pack_bf16(acc[ip][j][3] * scale, acc[ip + 1][j][3] * scale);
        *(uint4*)&rp[c32] = U;
      }
    }
    return;
  }

#pragma unroll
  for (int i = 0; i < 4; ++i) {
    int rg0 = tm * 128 + wr + i * 16 + lq * 4;
#pragma unroll
    for (int j = 0; j < 4; ++j) {
      int cg = tn * 128 + wc + j * 16 + lr;
#pragma unroll
      for (int r = 0; r < 4; ++r) {
        float v = acc[i][j][r] * scale;
        long off = (long)(rg0 + r) * ldc + cg;
        if (EPI == 0) ((float*)Cv)[off] = v;
        else          ((unsigned short*)Cv)[off] = f2bf(v);
      }
    }
  }
}

// ---------------- segment-local dilated attention (wave-independent) ----------
// 512-thread blocks, 8 INDEPENDENT waves each owning one 64-query block x all
// 256 keys; one shared V^T tile (staged once, single barrier). LDS 68.9 KB ->
// 2 blocks/CU (16 waves/CU) for latency hiding. w slice is wave-private.
__global__ __launch_bounds__(512, 2) void attn_kernel(
    const unsigned short* __restrict__ qb,    // [16384][1024] bf16, q*scale
    const unsigned short* __restrict__ kb,    // [2048][1024] bf16 dilated keys
    const unsigned short* __restrict__ vtb,   // sigma-permuted V^T
    unsigned short* __restrict__ attout)      // [16384][1024] bf16, col = h*64+d
{
  __shared__ unsigned short v_t[64 * 256];    // [f][g] swizzled, 32 KB
  __shared__ uint32_t w32[8][64][18];         // per-wave [q][col] slices, 36.9 KB

  // XCD-grouping remap (bijective, 512 = 8 x 64)
  const int u = (blockIdx.x & 7) * 64 + (blockIdx.x >> 3);
  const int quarter = u & 3, h = (u >> 2) & 15, s = (u >> 6) & 3, b = u >> 8;
  const int tid = threadIdx.x, w = tid >> 6, lane = tid & 63;
  const int lr = lane & 15, lq = lane >> 4;
  const long qrow0 = (long)b * 8192 + s * 2048 + quarter * 512 + w * 64;
  const int hc = h * 64;

  const unsigned short* kbase = kb + ((long)(b * 4 + s) * 256) * 1024 + hc;
  const unsigned short* vbase = vtb + ((long)(b * 4 + s) * 1024 + hc) * 256;

#pragma unroll
  for (int it = 0; it < 4; ++it) {
    int e = (it * 512 + tid) * 8;
    int f = e >> 8;
    int ch = (e >> 3) & 31;
    gload_lds16(vbase + (long)f * 256 + ((ch ^ (f & 7)) * 8), &v_t[e]);
  }

  const unsigned short* qbase = qb + qrow0 * 1024 + hc;
  short8 aq[4][2];
#pragma unroll
  for (int i = 0; i < 4; ++i)
#pragma unroll
    for (int kk = 0; kk < 2; ++kk)
      aq[i][kk] = *(const short8*)&qbase[(i * 16 + lr) * 1024 + (kk * 4 + lq) * 8];

  __syncthreads();   // V staged (only barrier in the kernel)

  short8 ones;
#pragma unroll
  for (int e = 0; e < 8; ++e) ones[e] = (short)0x3F80;  // bf16 1.0

  uint32_t (*wsl)[18] = w32[w];

  f32x4 acc_pv[4][4] = {};
  f32x4 acc_den[4] = {};

  short8 bkc[2][2], bkn[2][2];
#pragma unroll
  for (int j = 0; j < 2; ++j)
#pragma unroll
    for (int kk = 0; kk < 2; ++kk)
      bkc[j][kk] = *(const short8*)&kbase[(long)(j * 16 + lr) * 1024 + (kk * 4 + lq) * 8];

#pragma unroll
  for (int c = 0; c < 8; ++c) {
    if (c < 7) {
#pragma unroll
      for (int j = 0; j < 2; ++j)
#pragma unroll
        for (int kk = 0; kk < 2; ++kk)
          bkn[j][kk] = *(const short8*)
            &kbase[(long)((c + 1) * 32 + j * 16 + lr) * 1024 + (kk * 4 + lq) * 8];
    }

    f32x4 acc_s[4][2] = {};
#pragma unroll
    for (int kk = 0; kk < 2; ++kk)
#pragma unroll
      for (int i = 0; i < 4; ++i)
#pragma unroll
        for (int j = 0; j < 2; ++j)
          acc_s[i][j] = __builtin_amdgcn_mfma_f32_16x16x32_bf16(aq[i][kk], bkc[j][kk], acc_s[i][j], 0, 0, 0);

    float cmax[2];
#pragma unroll
    for (int j = 0; j < 2; ++j) {
      float m = -3.4e38f;
#pragma unroll
      for (int i = 0; i < 4; ++i)
#pragma unroll
        for (int r = 0; r < 4; ++r) m = fmaxf(m, acc_s[i][j][r]);
      m = fmaxf(m, __shfl_xor(m, 16));
      m = fmaxf(m, __shfl_xor(m, 32));
      cmax[j] = m;
    }

#pragma unroll
    for (int i = 0; i < 4; ++i) {
#pragma unroll
      for (int r = 0; r < 4; ++r) {
        int qq = i * 16 + lq * 4 + r;
        wsl[qq][lr] = pack_bf16(__expf(acc_s[i][0][r] - cmax[0]),
                                __expf(acc_s[i][1][r] - cmax[1]));
      }
    }

    short8 av[4];
#pragma unroll
    for (int ct = 0; ct < 4; ++ct) {
      int frow = ct * 16 + lr;
      av[ct] = *(const short8*)&v_t[frow * 256 + (((c * 4 + lq) ^ (frow & 7)) << 3)];
    }
#pragma unroll
    for (int qi = 0; qi < 4; ++qi) {
      short8 bw = *(const short8*)&wsl[qi * 16 + lr][lq * 4];
      acc_den[qi] = __builtin_amdgcn_mfma_f32_16x16x32_bf16(ones, bw, acc_den[qi], 0, 0, 0);
#pragma unroll
      for (int ct = 0; ct < 4; ++ct)
        acc_pv[qi][ct] = __builtin_amdgcn_mfma_f32_16x16x32_bf16(av[ct], bw, acc_pv[qi][ct], 0, 0, 0);
    }

#pragma unroll
    for (int j = 0; j < 2; ++j)
#pragma unroll
      for (int kk = 0; kk < 2; ++kk)
        bkc[j][kk] = bkn[j][kk];
  }

#pragma unroll
  for (int qi = 0; qi < 4; ++qi) {
    float inv = 1.0f / (acc_den[qi][0] + 1e-10f);
    long orow = (qrow0 + qi * 16 + lr) * 1024 + hc;
#pragma unroll
    for (int ct = 0; ct < 4; ++ct) {
      ushort4v p;
#pragma unroll
      for (int r = 0; r < 4; ++r) p[r] = f2bf(acc_pv[qi][ct][r] * inv);
      *(ushort4v*)&attout[orow + ct * 16 + lq * 4] = p;
    }
  }
}

extern "C" void kernel_launch(void* const* d_in, const int* in_sizes, int n_in,
                              void* d_out, int out_size, void* d_ws, size_t ws_size,
                              hipStream_t stream) {
  (void)in_sizes; (void)n_in; (void)out_size; (void)ws_size;
  const float* x    = (const float*)d_in[0];
  const float* Wqkv = (const float*)d_in[1];
  const float* Wout = (const float*)d_in[2];
  float* out = (float*)d_out;
  char* ws = (char*)d_ws;

  // workspace layout (80 MB). xb aliases attout: xb is dead before attn writes.
  unsigned short* xb     = (unsigned short*)(ws);               // 33,554,432 B
  unsigned short* attout = (unsigned short*)(ws);               // (same region)
  unsigned short* wqkvb  = (unsigned short*)(ws + 33554432);    //  6,291,456 B
  unsigned short* woutb  = (unsigned short*)(ws + 39845888);    //  2,097,152 B
  unsigned short* qbuf   = (unsigned short*)(ws + 41943040);    // 33,554,432 B
  unsigned short* kbuf   = (unsigned short*)(ws + 75497472);    //  4,194,304 B
  unsigned short* vtb    = (unsigned short*)(ws + 79691776);    //  4,194,304 B

  cvt_kernel<<<16384, 256, 0, stream>>>(x, xb, 16777216);
  cvt_kernel<<<3072, 256, 0, stream>>>(Wqkv, wqkvb, 3 * 1024 * 1024);
  cvt_kernel<<<1024, 256, 0, stream>>>(Wout, woutb, 1024 * 1024);

  // Q = (x @ Wq^T) * hd^-0.5  -> qbuf (8-phase 256^2)
  gemm8p<false><<<dim3(64, 4), 512, 0, stream>>>(xb, wqkvb, (void*)qbuf, 0.125f);
  // K,V at dilated rows (every 8th): K -> kbuf [2048][1024], V -> vtb (sigma V^T)
  gemm_bt<2><<<dim3(16, 16), 256, 0, stream>>>(
      xb, wqkvb + 1024 * 1024, (void*)kbuf, vtb, 1.0f, 8192, 1024, 1024);

  attn_kernel<<<512, 512, 0, stream>>>(qbuf, kbuf, vtb, attout);

  // final projection: out = attout @ Wout^T (f32 output, 8-phase 256^2)
  gemm8p<true><<<dim3(64, 4), 512, 0, stream>>>(attout, woutb, (void*)out, 1.0f);
}

// Round 11
// 165.945 us; speedup vs baseline: 1.0374x; 1.0374x over previous
//
#include <hip/hip_runtime.h>
#include <hip/hip_bf16.h>
#include <stdint.h>

// Problem constants: B=2, M=8192, D=1024, H=16, hd=64, SEG=2048, DIL=8
// => S=4 segments, Kn=256 dilated keys/segment, nb=32 query blocks of 64.

typedef __attribute__((ext_vector_type(8))) short short8;
typedef __attribute__((ext_vector_type(4))) float f32x4;
typedef __attribute__((ext_vector_type(4))) unsigned short ushort4v;

#define DEVI static __device__ __forceinline__

DEVI unsigned short f2bf(float f) {
  union { float f; uint32_t u; } v; v.f = f;
  return (unsigned short)((v.u + 0x7FFFu + ((v.u >> 16) & 1u)) >> 16);
}

// Pure-C bf16 pair pack (v_cvt_pk_bf16_f32 inline asm was broken - round 4/5).
DEVI uint32_t pack_bf16(float lo, float hi) {
  return (uint32_t)f2bf(lo) | ((uint32_t)f2bf(hi) << 16);
}

DEVI void gload_lds16(const void* g, void* l) {
  __builtin_amdgcn_global_load_lds((const __attribute__((address_space(1))) void*)g,
                                   (__attribute__((address_space(3))) void*)l,
                                   16, 0, 0);
}

// ---------------- f32 -> bf16 convert ----------------
__global__ void cvt_kernel(const float* __restrict__ in, unsigned short* __restrict__ out, int n) {
  int i = (blockIdx.x * 256 + threadIdx.x) * 4;
  if (i >= n) return;
  float4 f = *(const float4*)(in + i);
  uint2 o;
  o.x = (uint32_t)f2bf(f.x) | ((uint32_t)f2bf(f.y) << 16);
  o.y = (uint32_t)f2bf(f.z) | ((uint32_t)f2bf(f.w) << 16);
  *(uint2*)(out + i) = o;
}

// ======== 8-phase 256x256 GEMM: B-halves resident + single barrier ========
// 512 threads = 8 waves (2M x 4N); per-wave C 128x64, rows/cols interleaved
// across tile halves; gray-code quadrants (0,0)->(0,1)->(1,1)->(1,0).
// BOTH B-halves held in regs (bfr[2]) so per-K-tile reads = A0(8)+B0(4)+B1(4)
// +A1(8) = 24 -> 48 ds_read_b128/iter (m201 parity). ONE barrier per phase:
// {ds_read new frags; stage; lgkm0+schedbar; prio1 MFMA16 prio0; [vmcnt]; BAR}
// -> phase-p reads overlap phase-(p-1) MFMAs across waves.
// Stages: p0: buf1<-A0',B0'  p1: buf1<-B1'  p2: buf1<-A1'
//         p4: buf0<-A0'',B0''  p5: buf0<-B1''  p6: buf0<-A1''  (p4-6: t<7)
// Waits (counted, end-of-phase; 8 outstanding steady): p0:6 p1:6 p3:4 p4:6
// p5:6 p7:4; tail t=7: p4:2 p5:0. Per-unit retire/overwrite margins verified
// (every stage >=2 barriers after its unit's last reader; all same-window
// read/stage pairs hit different physical buffers).
#define STAGE_A(bf, hf, kt) do { \
  gload_lds16(Abase + (long)((hf) * 128 + srow0) * 1024 + (kt) * 64 + scol0, &smA[bf][hf][se0]); \
  gload_lds16(Abase + (long)((hf) * 128 + srow1) * 1024 + (kt) * 64 + scol1, &smA[bf][hf][se1]); \
} while (0)
#define STAGE_B(bf, hf, kt) do { \
  gload_lds16(Bbase + (long)((hf) * 128 + srow0) * 1024 + (kt) * 64 + scol0, &smB[bf][hf][se0]); \
  gload_lds16(Bbase + (long)((hf) * 128 + srow1) * 1024 + (kt) * 64 + scol1, &smB[bf][hf][se1]); \
} while (0)

template<bool OUT_F32>
__global__ __launch_bounds__(512, 1) void gemm8p(
    const unsigned short* __restrict__ A, const unsigned short* __restrict__ B,
    void* __restrict__ Cv, float scale)
{
  __shared__ unsigned short smA[2][2][128 * 64];   // [buf][half][r][k] swizzled
  __shared__ unsigned short smB[2][2][128 * 64];
  const int tid = threadIdx.x;
  const int tm = blockIdx.x, tn = blockIdx.y;
  const int w = tid >> 6, lane = tid & 63;
  const int wm = w >> 2, wn = w & 3;
  const int lr = lane & 15, lq = lane >> 4;

  const int e0 = tid * 8,        e1 = (512 + tid) * 8;
  const int srow0 = e0 >> 6,     srow1 = e1 >> 6;
  const int sc0 = (e0 >> 3) & 7, sc1 = (e1 >> 3) & 7;
  const int scol0 = (sc0 ^ (srow0 & 7)) * 8, scol1 = (sc1 ^ (srow1 & 7)) * 8;
  const int se0 = e0, se1 = e1;

  const unsigned short* Abase = A + (long)tm * 256 * 1024;
  const unsigned short* Bbase = B + (long)tn * 256 * 1024;

  f32x4 acc[8][4] = {};
  short8 af[4][2];        // current A-half fragments (persist 2 phases)
  short8 bfr[2][2][2];    // BOTH B-half fragments [half][nj2][kk]

  // prologue: stage tile 0 into buf0 in consumption order A0,B0 | B1 | A1
  STAGE_A(0, 0, 0); STAGE_B(0, 0, 0); STAGE_B(0, 1, 0); STAGE_A(0, 1, 0);
  asm volatile("s_waitcnt vmcnt(4)" ::: "memory");
  __builtin_amdgcn_s_barrier();
  asm volatile("" ::: "memory");

  for (int t = 0; t < 8; ++t) {
#pragma unroll
    for (int p = 0; p < 8; ++p) {
      const int o = p >> 2;            // LDS buf: 0 for kt=2t, 1 for kt=2t+1
      const int q = p & 3;
      const int a = (p >> 1) & 1;      // A-half: 0,0,1,1
      const int b = a ^ (q & 1);       // B-half: 0,1,1,0 (gray)

      // ---- ds_read only NEW fragments
      if (q == 0 || q == 2) {          // new A-half (8 x b128)
#pragma unroll
        for (int mi2 = 0; mi2 < 4; ++mi2) {
          int r = wm * 64 + mi2 * 16 + lr;
#pragma unroll
          for (int kk = 0; kk < 2; ++kk) {
            int kc = kk * 4 + lq;
            af[mi2][kk] = *(const short8*)&smA[o][a][r * 64 + ((kc ^ (r & 7)) * 8)];
          }
        }
      }
      if (q == 0 || q == 1) {          // new B-half b (4 x b128), kept resident
#pragma unroll
        for (int nj2 = 0; nj2 < 2; ++nj2) {
          int r = wn * 32 + nj2 * 16 + lr;
#pragma unroll
          for (int kk = 0; kk < 2; ++kk) {
            int kc = kk * 4 + lq;
            bfr[b][nj2][kk] = *(const short8*)&smB[o][b][r * 64 + ((kc ^ (r & 7)) * 8)];
          }
        }
      }

      // ---- stage
      switch (p) {
        case 0: STAGE_A(1, 0, 2 * t + 1); STAGE_B(1, 0, 2 * t + 1); break;
        case 1: STAGE_B(1, 1, 2 * t + 1); break;
        case 2: STAGE_A(1, 1, 2 * t + 1); break;
        case 4: if (t < 7) { STAGE_A(0, 0, 2 * t + 2); STAGE_B(0, 0, 2 * t + 2); } break;
        case 5: if (t < 7) STAGE_B(0, 1, 2 * t + 2); break;
        case 6: if (t < 7) STAGE_A(0, 1, 2 * t + 2); break;
      }

      // ---- drain this phase's ds_reads, MFMA cluster
      if (q != 3) {
        asm volatile("s_waitcnt lgkmcnt(0)" ::: "memory");
        __builtin_amdgcn_sched_barrier(0);
      }

      __builtin_amdgcn_s_setprio(1);
#pragma unroll
      for (int kk = 0; kk < 2; ++kk)
#pragma unroll
        for (int mi2 = 0; mi2 < 4; ++mi2)
#pragma unroll
          for (int nj2 = 0; nj2 < 2; ++nj2)
            acc[a * 4 + mi2][b * 2 + nj2] = __builtin_amdgcn_mfma_f32_16x16x32_bf16(
                af[mi2][kk], bfr[b][nj2][kk], acc[a * 4 + mi2][b * 2 + nj2], 0, 0, 0);
      __builtin_amdgcn_s_setprio(0);

      // ---- counted wait + single barrier
      if (t < 7) {
        if (p == 0 || p == 1 || p == 4 || p == 5)
          asm volatile("s_waitcnt vmcnt(6)" ::: "memory");
        else if (p == 3 || p == 7)
          asm volatile("s_waitcnt vmcnt(4)" ::: "memory");
      } else {
        if (p == 0 || p == 1)      asm volatile("s_waitcnt vmcnt(6)" ::: "memory");
        else if (p == 3)           asm volatile("s_waitcnt vmcnt(4)" ::: "memory");
        else if (p == 4)           asm volatile("s_waitcnt vmcnt(2)" ::: "memory");
        else if (p == 5)           asm volatile("s_waitcnt vmcnt(0)" ::: "memory");
      }
      __builtin_amdgcn_s_barrier();
      asm volatile("" ::: "memory");
    }
  }

  // ---- epilogue
  const int row0 = tm * 256 + wm * 64 + lq * 4;
  const int col0 = tn * 256 + wn * 32 + lr;
#pragma unroll
  for (int mi = 0; mi < 8; ++mi) {
    int row = row0 + (mi & 3) * 16 + (mi >> 2) * 128;
#pragma unroll
    for (int nj = 0; nj < 4; ++nj) {
      int col = col0 + (nj & 1) * 16 + (nj >> 1) * 128;
#pragma unroll
      for (int rr = 0; rr < 4; ++rr) {
        float v = acc[mi][nj][rr] * scale;
        long off = (long)(row + rr) * 1024 + col;
        if (OUT_F32) ((float*)Cv)[off] = v;
        else         ((unsigned short*)Cv)[off] = f2bf(v);
      }
    }
  }
}

// ---------------- 128^2 GEMM, kept for the KV split ----------------
// EPI 2: tn<8 -> bf16 K rows to Cv; tn>=8 -> V TRANSPOSED + sigma-permuted to
// Cv2 (row = seg*1024+f; u32 col c packs tokens (32*(c>>4)+(c&15), +16)).
template<int EPI>
__global__ __launch_bounds__(256, 2) void gemm_bt(
    const unsigned short* __restrict__ A, const unsigned short* __restrict__ B,
    void* __restrict__ Cv, unsigned short* __restrict__ Cv2,
    float scale, long a_row_stride, int ldc, int K)
{
  __shared__ unsigned short smA[128 * 64];
  __shared__ unsigned short smB[128 * 64];
  const int tid = threadIdx.x;
  const int tm = blockIdx.x, tn = blockIdx.y;
  const int w = tid >> 6, lane = tid & 63;
  const int wr = (w >> 1) * 64, wc = (w & 1) * 64;
  const int lr = lane & 15, lq = lane >> 4;

  int se[4], srow[4], scol[4];
#pragma unroll
  for (int i = 0; i < 4; ++i) {
    int e = (i * 256 + tid) * 8;
    int r = e >> 6;
    int cc = (e >> 3) & 7;
    se[i] = e; srow[i] = r; scol[i] = (cc ^ (r & 7)) * 8;
  }

  f32x4 acc[4][4] = {};

  for (int kt = 0; kt < K / 64; ++kt) {
    if (kt) __syncthreads();
#pragma unroll
    for (int i = 0; i < 4; ++i)
      gload_lds16(A + (long)(tm * 128 + srow[i]) * a_row_stride + kt * 64 + scol[i], &smA[se[i]]);
#pragma unroll
    for (int i = 0; i < 4; ++i)
      gload_lds16(B + (long)(tn * 128 + srow[i]) * K + kt * 64 + scol[i], &smB[se[i]]);
    __syncthreads();

#pragma unroll
    for (int kk = 0; kk < 2; ++kk) {
      int kc = kk * 4 + lq;
      short8 af[4], bfm[4];
#pragma unroll
      for (int i = 0; i < 4; ++i) {
        int row = wr + i * 16 + lr;
        af[i] = *(const short8*)&smA[row * 64 + ((kc ^ (row & 7)) * 8)];
      }
#pragma unroll
      for (int j = 0; j < 4; ++j) {
        int row = wc + j * 16 + lr;
        bfm[j] = *(const short8*)&smB[row * 64 + ((kc ^ (row & 7)) * 8)];
      }
#pragma unroll
      for (int i = 0; i < 4; ++i)
#pragma unroll
        for (int j = 0; j < 4; ++j)
          acc[i][j] = __builtin_amdgcn_mfma_f32_16x16x32_bf16(af[i], bfm[j], acc[i][j], 0, 0, 0);
    }
  }

  if (EPI == 2 && tn >= 8) {
    const int fbase = (tn - 8) * 128 + wc;
#pragma unroll
    for (int ip = 0; ip < 4; ip += 2) {
      int t0 = tm * 128 + wr + ip * 16 + lq * 4;
      int seg = t0 >> 8;
      int ts  = t0 & 255;
      int c32 = (ts >> 5) * 16 + (ts & 15);
#pragma unroll
      for (int j = 0; j < 4; ++j) {
        int f = fbase + j * 16 + lr;
        uint32_t* rp = (uint32_t*)&Cv2[((long)(seg * 1024 + f)) * 256];
        uint4 U;
        U.x = pack_bf16(acc[ip][j][0] * scale, acc[ip + 1][j][0] * scale);
        U.y = pack_bf16(acc[ip][j][1] * scale, acc[ip + 1][j][1] * scale);
        U.z = pack_bf16(acc[ip][j][2] * scale, acc[ip + 1][j][2] * scale);
        U.w = pack_bf16(acc[ip][j][3] * scale, acc[ip + 1][j][3] * scale);
        *(uint4*)&rp[c32] = U;
      }
    }
    return;
  }

#pragma unroll
  for (int i = 0; i < 4; ++i) {
    int rg0 = tm * 128 + wr + i * 16 + lq * 4;
#pragma unroll
    for (int j = 0; j < 4; ++j) {
      int cg = tn * 128 + wc + j * 16 + lr;
#pragma unroll
      for (int r = 0; r < 4; ++r) {
        float v = acc[i][j][r] * scale;
        long off = (long)(rg0 + r) * ldc + cg;
        if (EPI == 0) ((float*)Cv)[off] = v;
        else          ((unsigned short*)Cv)[off] = f2bf(v);
      }
    }
  }
}

// ---------------- segment-local dilated attention, 2-deep pipeline ----------
// 512-thread blocks, 8 independent waves each owning one 64-query block x 256
// keys. 2-DEEP software pipeline with named register banks (sA/sB, bk0/bk1):
// each step issues chunk-(c+1)'s QK^T MFMAs (independent) BEFORE chunk-c's
// softmax VALU work -> MFMA pipe overlaps VALU/trans pipe instead of the
// serial QKT->max->exp->LDS->PV chain. K prefetch stays 2 chunks ahead.
// w32 row stride 20 u32: b128-aligned; writes 2-way (free), bw reads span-
// start (5*lr+lq)%8 exactly even -> conflict-free (was 4-way at stride 18).
__global__ __launch_bounds__(512, 2) void attn_kernel(
    const unsigned short* __restrict__ qb,    // [16384][1024] bf16, q*scale
    const unsigned short* __restrict__ kb,    // [2048][1024] bf16 dilated keys
    const unsigned short* __restrict__ vtb,   // sigma-permuted V^T
    unsigned short* __restrict__ attout)      // [16384][1024] bf16, col = h*64+d
{
  __shared__ unsigned short v_t[64 * 256];    // [f][g] swizzled, 32 KB
  __shared__ uint32_t w32[8][64][20];         // per-wave [q][col] slices, 40 KB

  const int u = (blockIdx.x & 7) * 64 + (blockIdx.x >> 3);
  const int quarter = u & 3, h = (u >> 2) & 15, s = (u >> 6) & 3, b = u >> 8;
  const int tid = threadIdx.x, w = tid >> 6, lane = tid & 63;
  const int lr = lane & 15, lq = lane >> 4;
  const long qrow0 = (long)b * 8192 + s * 2048 + quarter * 512 + w * 64;
  const int hc = h * 64;

  const unsigned short* kbase = kb + ((long)(b * 4 + s) * 256) * 1024 + hc;
  const unsigned short* vbase = vtb + ((long)(b * 4 + s) * 1024 + hc) * 256;

#pragma unroll
  for (int it = 0; it < 4; ++it) {
    int e = (it * 512 + tid) * 8;
    int f = e >> 8;
    int ch = (e >> 3) & 31;
    gload_lds16(vbase + (long)f * 256 + ((ch ^ (f & 7)) * 8), &v_t[e]);
  }

  const unsigned short* qbase = qb + qrow0 * 1024 + hc;
  short8 aq[4][2];
#pragma unroll
  for (int i = 0; i < 4; ++i)
#pragma unroll
    for (int kk = 0; kk < 2; ++kk)
      aq[i][kk] = *(const short8*)&qbase[(i * 16 + lr) * 1024 + (kk * 4 + lq) * 8];

  __syncthreads();   // V staged (only barrier in the kernel)

  short8 ones;
#pragma unroll
  for (int e = 0; e < 8; ++e) ones[e] = (short)0x3F80;  // bf16 1.0

  uint32_t (*wsl)[20] = w32[w];

  f32x4 acc_pv[4][4] = {};
  f32x4 acc_den[4] = {};
  short8 bk0[2][2], bk1[2][2];
  f32x4 sA[4][2], sB[4][2];

#define LOADK(BK, CC) do { \
  _Pragma("unroll") for (int j = 0; j < 2; ++j) \
    _Pragma("unroll") for (int kk = 0; kk < 2; ++kk) \
      BK[j][kk] = *(const short8*)&kbase[(long)((CC) * 32 + j * 16 + lr) * 1024 + (kk * 4 + lq) * 8]; \
} while (0)

#define QKT(S, BK) do { \
  _Pragma("unroll") for (int i = 0; i < 4; ++i) \
    _Pragma("unroll") for (int j = 0; j < 2; ++j) { \
      f32x4 z = {0.f, 0.f, 0.f, 0.f}; S[i][j] = z; } \
  _Pragma("unroll") for (int kk = 0; kk < 2; ++kk) \
    _Pragma("unroll") for (int i = 0; i < 4; ++i) \
      _Pragma("unroll") for (int j = 0; j < 2; ++j) \
        S[i][j] = __builtin_amdgcn_mfma_f32_16x16x32_bf16(aq[i][kk], BK[j][kk], S[i][j], 0, 0, 0); \
} while (0)

#define SOFTPV(S, CC) do { \
  float c0 = -3.4e38f, c1 = -3.4e38f; \
  _Pragma("unroll") for (int i = 0; i < 4; ++i) \
    _Pragma("unroll") for (int r = 0; r < 4; ++r) { \
      c0 = fmaxf(c0, S[i][0][r]); c1 = fmaxf(c1, S[i][1][r]); } \
  c0 = fmaxf(c0, __shfl_xor(c0, 16)); c0 = fmaxf(c0, __shfl_xor(c0, 32)); \
  c1 = fmaxf(c1, __shfl_xor(c1, 16)); c1 = fmaxf(c1, __shfl_xor(c1, 32)); \
  _Pragma("unroll") for (int i = 0; i < 4; ++i) \
    _Pragma("unroll") for (int r = 0; r < 4; ++r) { \
      int qq = i * 16 + lq * 4 + r; \
      wsl[qq][lr] = pack_bf16(__expf(S[i][0][r] - c0), __expf(S[i][1][r] - c1)); } \
  short8 av_[4]; \
  _Pragma("unroll") for (int ct = 0; ct < 4; ++ct) { \
    int frow = ct * 16 + lr; \
    av_[ct] = *(const short8*)&v_t[frow * 256 + ((((CC) * 4 + lq) ^ (frow & 7)) << 3)]; } \
  _Pragma("unroll") for (int qi = 0; qi < 4; ++qi) { \
    short8 bw = *(const short8*)&wsl[qi * 16 + lr][lq * 4]; \
    acc_den[qi] = __builtin_amdgcn_mfma_f32_16x16x32_bf16(ones, bw, acc_den[qi], 0, 0, 0); \
    _Pragma("unroll") for (int ct = 0; ct < 4; ++ct) \
      acc_pv[qi][ct] = __builtin_amdgcn_mfma_f32_16x16x32_bf16(av_[ct], bw, acc_pv[qi][ct], 0, 0, 0); } \
} while (0)

  // prologue: K chunks 0,1 in regs; scores for chunk 0
  LOADK(bk0, 0);
  LOADK(bk1, 1);
  QKT(sA, bk0);

  // 2-deep pipeline, unrolled (named banks; no runtime indexing)
  LOADK(bk0, 2); QKT(sB, bk1); SOFTPV(sA, 0);
  LOADK(bk1, 3); QKT(sA, bk0); SOFTPV(sB, 1);
  LOADK(bk0, 4); QKT(sB, bk1); SOFTPV(sA, 2);
  LOADK(bk1, 5); QKT(sA, bk0); SOFTPV(sB, 3);
  LOADK(bk0, 6); QKT(sB, bk1); SOFTPV(sA, 4);
  LOADK(bk1, 7); QKT(sA, bk0); SOFTPV(sB, 5);
                 QKT(sB, bk1); SOFTPV(sA, 6);
                               SOFTPV(sB, 7);

  // ---- epilogue: out[q][f] = num/den, packed 8B stores
#pragma unroll
  for (int qi = 0; qi < 4; ++qi) {
    float inv = 1.0f / (acc_den[qi][0] + 1e-10f);
    long orow = (qrow0 + qi * 16 + lr) * 1024 + hc;
#pragma unroll
    for (int ct = 0; ct < 4; ++ct) {
      ushort4v p;
#pragma unroll
      for (int r = 0; r < 4; ++r) p[r] = f2bf(acc_pv[qi][ct][r] * inv);
      *(ushort4v*)&attout[orow + ct * 16 + lq * 4] = p;
    }
  }
}

extern "C" void kernel_launch(void* const* d_in, const int* in_sizes, int n_in,
                              void* d_out, int out_size, void* d_ws, size_t ws_size,
                              hipStream_t stream) {
  (void)in_sizes; (void)n_in; (void)out_size; (void)ws_size;
  const float* x    = (const float*)d_in[0];
  const float* Wqkv = (const float*)d_in[1];
  const float* Wout = (const float*)d_in[2];
  float* out = (float*)d_out;
  char* ws = (char*)d_ws;

  // workspace layout (80 MB). xb aliases attout: xb is dead before attn writes.
  unsigned short* xb     = (unsigned short*)(ws);               // 33,554,432 B
  unsigned short* attout = (unsigned short*)(ws);               // (same region)
  unsigned short* wqkvb  = (unsigned short*)(ws + 33554432);    //  6,291,456 B
  unsigned short* woutb  = (unsigned short*)(ws + 39845888);    //  2,097,152 B
  unsigned short* qbuf   = (unsigned short*)(ws + 41943040);    // 33,554,432 B
  unsigned short* kbuf   = (unsigned short*)(ws + 75497472);    //  4,194,304 B
  unsigned short* vtb    = (unsigned short*)(ws + 79691776);    //  4,194,304 B

  cvt_kernel<<<16384, 256, 0, stream>>>(x, xb, 16777216);
  cvt_kernel<<<3072, 256, 0, stream>>>(Wqkv, wqkvb, 3 * 1024 * 1024);
  cvt_kernel<<<1024, 256, 0, stream>>>(Wout, woutb, 1024 * 1024);

  // Q = (x @ Wq^T) * hd^-0.5  -> qbuf (8-phase 256^2)
  gemm8p<false><<<dim3(64, 4), 512, 0, stream>>>(xb, wqkvb, (void*)qbuf, 0.125f);
  // K,V at dilated rows (every 8th): K -> kbuf [2048][1024], V -> vtb (sigma V^T)
  gemm_bt<2><<<dim3(16, 16), 256, 0, stream>>>(
      xb, wqkvb + 1024 * 1024, (void*)kbuf, vtb, 1.0f, 8192, 1024, 1024);

  attn_kernel<<<512, 512, 0, stream>>>(qbuf, kbuf, vtb, attout);

  // final projection: out = attout @ Wout^T (f32 output, 8-phase 256^2)
  gemm8p<true><<<dim3(64, 4), 512, 0, stream>>>(attout, woutb, (void*)out, 1.0f);
}

// Round 12
// 165.815 us; speedup vs baseline: 1.0383x; 1.0008x over previous
//
#include <hip/hip_runtime.h>
#include <hip/hip_bf16.h>
#include <stdint.h>

// Problem constants: B=2, M=8192, D=1024, H=16, hd=64, SEG=2048, DIL=8
// => S=4 segments, Kn=256 dilated keys/segment, nb=32 query blocks of 64.

typedef __attribute__((ext_vector_type(8))) short short8;
typedef __attribute__((ext_vector_type(4))) float f32x4;
typedef __attribute__((ext_vector_type(4))) unsigned short ushort4v;

#define DEVI static __device__ __forceinline__

DEVI unsigned short f2bf(float f) {
  union { float f; uint32_t u; } v; v.f = f;
  return (unsigned short)((v.u + 0x7FFFu + ((v.u >> 16) & 1u)) >> 16);
}

// Pure-C bf16 pair pack (v_cvt_pk_bf16_f32 inline asm was broken - round 4/5).
DEVI uint32_t pack_bf16(float lo, float hi) {
  return (uint32_t)f2bf(lo) | ((uint32_t)f2bf(hi) << 16);
}

DEVI void gload_lds16(const void* g, void* l) {
  __builtin_amdgcn_global_load_lds((const __attribute__((address_space(1))) void*)g,
                                   (__attribute__((address_space(3))) void*)l,
                                   16, 0, 0);
}

// ---------------- f32 -> bf16 convert ----------------
__global__ void cvt_kernel(const float* __restrict__ in, unsigned short* __restrict__ out, int n) {
  int i = (blockIdx.x * 256 + threadIdx.x) * 4;
  if (i >= n) return;
  float4 f = *(const float4*)(in + i);
  uint2 o;
  o.x = (uint32_t)f2bf(f.x) | ((uint32_t)f2bf(f.y) << 16);
  o.y = (uint32_t)f2bf(f.z) | ((uint32_t)f2bf(f.w) << 16);
  *(uint2*)(out + i) = o;
}

// ======== 8-phase 256x256 GEMM: m201 rhythm, gray-code, batch stages ========
// 512 threads = 8 waves (2M x 4N); per-wave C 128x64, rows/cols interleaved
// across tile halves; gray-code quadrants (0,0)->(0,1)->(1,1)->(1,0):
// A-frags reload q=0,2 (8 rds), B-halves both resident, loaded q=0,1 (4 rds)
// -> 48 ds_read_b128/iter.  Phase rhythm (m201/r8-proven 2-barrier):
//   {ds_read new frags; stage; BAR; lgkm0+schedbar; prio1 MFMA16 prio0;
//    [vmcnt]; BAR}
// Batch stages, 2 units (4 gloads) at p0,p2,p4,p6 with 4-phase lag:
//   p0: buf1<-A0',B0'   p2: buf1<-B1',A1'
//   p4: buf0<-A0'',B0'' p6: buf0<-B1'',A1''   (p4,p6 skipped at t=7)
// Waits: vmcnt(4) at ENDS of p0,p3,p4,p7 only (4/iter). Proof: at each wait
// exactly 8 loads outstanding (two 4-load batches); vmcnt(4) retires the
// older batch, which is exactly what the next 1-3 phases read. Overwrites
// are >=4 phases (>=8 barriers) after the unit's last LDS read. Prologue
// stages 8 loads + vmcnt(4) (retires A0,B0; B1,A1 retired by end-p0 wait).
// Tail t=7: end-p4 vmcnt(0), end-p7 no wait; loop exits drained.
#define STAGE_A(bf, hf, kt) do { \
  gload_lds16(Abase + (long)((hf) * 128 + srow0) * 1024 + (kt) * 64 + scol0, &smA[bf][hf][se0]); \
  gload_lds16(Abase + (long)((hf) * 128 + srow1) * 1024 + (kt) * 64 + scol1, &smA[bf][hf][se1]); \
} while (0)
#define STAGE_B(bf, hf, kt) do { \
  gload_lds16(Bbase + (long)((hf) * 128 + srow0) * 1024 + (kt) * 64 + scol0, &smB[bf][hf][se0]); \
  gload_lds16(Bbase + (long)((hf) * 128 + srow1) * 1024 + (kt) * 64 + scol1, &smB[bf][hf][se1]); \
} while (0)

template<bool OUT_F32>
__global__ __launch_bounds__(512, 1) void gemm8p(
    const unsigned short* __restrict__ A, const unsigned short* __restrict__ B,
    void* __restrict__ Cv, float scale)
{
  __shared__ unsigned short smA[2][2][128 * 64];   // [buf][half][r][k] swizzled
  __shared__ unsigned short smB[2][2][128 * 64];
  const int tid = threadIdx.x;
  const int tm = blockIdx.x, tn = blockIdx.y;
  const int w = tid >> 6, lane = tid & 63;
  const int wm = w >> 2, wn = w & 3;
  const int lr = lane & 15, lq = lane >> 4;

  const int e0 = tid * 8,        e1 = (512 + tid) * 8;
  const int srow0 = e0 >> 6,     srow1 = e1 >> 6;
  const int sc0 = (e0 >> 3) & 7, sc1 = (e1 >> 3) & 7;
  const int scol0 = (sc0 ^ (srow0 & 7)) * 8, scol1 = (sc1 ^ (srow1 & 7)) * 8;
  const int se0 = e0, se1 = e1;

  const unsigned short* Abase = A + (long)tm * 256 * 1024;
  const unsigned short* Bbase = B + (long)tn * 256 * 1024;

  f32x4 acc[8][4] = {};
  short8 af[4][2];        // current A-half fragments (persist 2 phases)
  short8 bfr[2][2][2];    // BOTH B-half fragments [half][nj2][kk]

  // prologue: stage tile 0 into buf0 (A0,B0 first 4 loads; B1,A1 next 4)
  STAGE_A(0, 0, 0); STAGE_B(0, 0, 0); STAGE_B(0, 1, 0); STAGE_A(0, 1, 0);
  asm volatile("s_waitcnt vmcnt(4)" ::: "memory");
  __builtin_amdgcn_s_barrier();
  asm volatile("" ::: "memory");

  for (int t = 0; t < 8; ++t) {
#pragma unroll
    for (int p = 0; p < 8; ++p) {
      const int o = p >> 2;            // LDS buf: 0 for kt=2t, 1 for kt=2t+1
      const int q = p & 3;
      const int a = (p >> 1) & 1;      // A-half: 0,0,1,1
      const int b = a ^ (q & 1);       // B-half: 0,1,1,0 (gray)

      // ---- ds_read only NEW fragments for this phase
      if (q == 0 || q == 2) {          // new A-half (8 x b128)
#pragma unroll
        for (int mi2 = 0; mi2 < 4; ++mi2) {
          int r = wm * 64 + mi2 * 16 + lr;
#pragma unroll
          for (int kk = 0; kk < 2; ++kk) {
            int kc = kk * 4 + lq;
            af[mi2][kk] = *(const short8*)&smA[o][a][r * 64 + ((kc ^ (r & 7)) * 8)];
          }
        }
      }
      if (q == 0 || q == 1) {          // new B-half b (4 x b128), kept resident
#pragma unroll
        for (int nj2 = 0; nj2 < 2; ++nj2) {
          int r = wn * 32 + nj2 * 16 + lr;
#pragma unroll
          for (int kk = 0; kk < 2; ++kk) {
            int kc = kk * 4 + lq;
            bfr[b][nj2][kk] = *(const short8*)&smB[o][b][r * 64 + ((kc ^ (r & 7)) * 8)];
          }
        }
      }

      // ---- batch stage (2 units = 4 gloads) at p0,p2,p4,p6
      switch (p) {
        case 0: STAGE_A(1, 0, 2 * t + 1); STAGE_B(1, 0, 2 * t + 1); break;
        case 2: STAGE_B(1, 1, 2 * t + 1); STAGE_A(1, 1, 2 * t + 1); break;
        case 4: if (t < 7) { STAGE_A(0, 0, 2 * t + 2); STAGE_B(0, 0, 2 * t + 2); } break;
        case 6: if (t < 7) { STAGE_B(0, 1, 2 * t + 2); STAGE_A(0, 1, 2 * t + 2); } break;
      }

      // ---- first barrier; drain ds_reads during barrier spread; MFMA
      __builtin_amdgcn_s_barrier();
      if (q != 3) {
        asm volatile("s_waitcnt lgkmcnt(0)" ::: "memory");
        __builtin_amdgcn_sched_barrier(0);
      }

      __builtin_amdgcn_s_setprio(1);
#pragma unroll
      for (int kk = 0; kk < 2; ++kk)
#pragma unroll
        for (int mi2 = 0; mi2 < 4; ++mi2)
#pragma unroll
          for (int nj2 = 0; nj2 < 2; ++nj2)
            acc[a * 4 + mi2][b * 2 + nj2] = __builtin_amdgcn_mfma_f32_16x16x32_bf16(
                af[mi2][kk], bfr[b][nj2][kk], acc[a * 4 + mi2][b * 2 + nj2], 0, 0, 0);
      __builtin_amdgcn_s_setprio(0);

      // ---- counted wait (ends of p0,p3,p4,p7 only) + second barrier
      if (t < 7) {
        if (p == 0 || p == 3 || p == 4 || p == 7)
          asm volatile("s_waitcnt vmcnt(4)" ::: "memory");
      } else {
        if (p == 0 || p == 3)  asm volatile("s_waitcnt vmcnt(4)" ::: "memory");
        else if (p == 4)       asm volatile("s_waitcnt vmcnt(0)" ::: "memory");
      }
      __builtin_amdgcn_s_barrier();
      asm volatile("" ::: "memory");
    }
  }

  // ---- epilogue
  const int row0 = tm * 256 + wm * 64 + lq * 4;
  const int col0 = tn * 256 + wn * 32 + lr;
#pragma unroll
  for (int mi = 0; mi < 8; ++mi) {
    int row = row0 + (mi & 3) * 16 + (mi >> 2) * 128;
#pragma unroll
    for (int nj = 0; nj < 4; ++nj) {
      int col = col0 + (nj & 1) * 16 + (nj >> 1) * 128;
#pragma unroll
      for (int rr = 0; rr < 4; ++rr) {
        float v = acc[mi][nj][rr] * scale;
        long off = (long)(row + rr) * 1024 + col;
        if (OUT_F32) ((float*)Cv)[off] = v;
        else         ((unsigned short*)Cv)[off] = f2bf(v);
      }
    }
  }
}

// ---------------- 128^2 GEMM, kept for the KV split ----------------
// EPI 2: tn<8 -> bf16 K rows to Cv; tn>=8 -> V TRANSPOSED + sigma-permuted to
// Cv2 (row = seg*1024+f; u32 col c packs tokens (32*(c>>4)+(c&15), +16)).
template<int EPI>
__global__ __launch_bounds__(256, 2) void gemm_bt(
    const unsigned short* __restrict__ A, const unsigned short* __restrict__ B,
    void* __restrict__ Cv, unsigned short* __restrict__ Cv2,
    float scale, long a_row_stride, int ldc, int K)
{
  __shared__ unsigned short smA[128 * 64];
  __shared__ unsigned short smB[128 * 64];
  const int tid = threadIdx.x;
  const int tm = blockIdx.x, tn = blockIdx.y;
  const int w = tid >> 6, lane = tid & 63;
  const int wr = (w >> 1) * 64, wc = (w & 1) * 64;
  const int lr = lane & 15, lq = lane >> 4;

  int se[4], srow[4], scol[4];
#pragma unroll
  for (int i = 0; i < 4; ++i) {
    int e = (i * 256 + tid) * 8;
    int r = e >> 6;
    int cc = (e >> 3) & 7;
    se[i] = e; srow[i] = r; scol[i] = (cc ^ (r & 7)) * 8;
  }

  f32x4 acc[4][4] = {};

  for (int kt = 0; kt < K / 64; ++kt) {
    if (kt) __syncthreads();
#pragma unroll
    for (int i = 0; i < 4; ++i)
      gload_lds16(A + (long)(tm * 128 + srow[i]) * a_row_stride + kt * 64 + scol[i], &smA[se[i]]);
#pragma unroll
    for (int i = 0; i < 4; ++i)
      gload_lds16(B + (long)(tn * 128 + srow[i]) * K + kt * 64 + scol[i], &smB[se[i]]);
    __syncthreads();

#pragma unroll
    for (int kk = 0; kk < 2; ++kk) {
      int kc = kk * 4 + lq;
      short8 af[4], bfm[4];
#pragma unroll
      for (int i = 0; i < 4; ++i) {
        int row = wr + i * 16 + lr;
        af[i] = *(const short8*)&smA[row * 64 + ((kc ^ (row & 7)) * 8)];
      }
#pragma unroll
      for (int j = 0; j < 4; ++j) {
        int row = wc + j * 16 + lr;
        bfm[j] = *(const short8*)&smB[row * 64 + ((kc ^ (row & 7)) * 8)];
      }
#pragma unroll
      for (int i = 0; i < 4; ++i)
#pragma unroll
        for (int j = 0; j < 4; ++j)
          acc[i][j] = __builtin_amdgcn_mfma_f32_16x16x32_bf16(af[i], bfm[j], acc[i][j], 0, 0, 0);
    }
  }

  if (EPI == 2 && tn >= 8) {
    const int fbase = (tn - 8) * 128 + wc;
#pragma unroll
    for (int ip = 0; ip < 4; ip += 2) {
      int t0 = tm * 128 + wr + ip * 16 + lq * 4;
      int seg = t0 >> 8;
      int ts  = t0 & 255;
      int c32 = (ts >> 5) * 16 + (ts & 15);
#pragma unroll
      for (int j = 0; j < 4; ++j) {
        int f = fbase + j * 16 + lr;
        uint32_t* rp = (uint32_t*)&Cv2[((long)(seg * 1024 + f)) * 256];
        uint4 U;
        U.x = pack_bf16(acc[ip][j][0] * scale, acc[ip + 1][j][0] * scale);
        U.y = pack_bf16(acc[ip][j][1] * scale, acc[ip + 1][j][1] * scale);
        U.z = pack_bf16(acc[ip][j][2] * scale, acc[ip + 1][j][2] * scale);
        U.w = pack_bf16(acc[ip][j][3] * scale, acc[ip + 1][j][3] * scale);
        *(uint4*)&rp[c32] = U;
      }
    }
    return;
  }

#pragma unroll
  for (int i = 0; i < 4; ++i) {
    int rg0 = tm * 128 + wr + i * 16 + lq * 4;
#pragma unroll
    for (int j = 0; j < 4; ++j) {
      int cg = tn * 128 + wc + j * 16 + lr;
#pragma unroll
      for (int r = 0; r < 4; ++r) {
        float v = acc[i][j][r] * scale;
        long off = (long)(rg0 + r) * ldc + cg;
        if (EPI == 0) ((float*)Cv)[off] = v;
        else          ((unsigned short*)Cv)[off] = f2bf(v);
      }
    }
  }
}

// ---------------- segment-local dilated attention, 2-deep pipeline ----------
// (unchanged from round 11: 512-thread blocks, 8 independent waves, 2-deep
// software pipeline with named banks; w32 stride 20; zero main-loop barriers)
__global__ __launch_bounds__(512, 2) void attn_kernel(
    const unsigned short* __restrict__ qb,    // [16384][1024] bf16, q*scale
    const unsigned short* __restrict__ kb,    // [2048][1024] bf16 dilated keys
    const unsigned short* __restrict__ vtb,   // sigma-permuted V^T
    unsigned short* __restrict__ attout)      // [16384][1024] bf16, col = h*64+d
{
  __shared__ unsigned short v_t[64 * 256];    // [f][g] swizzled, 32 KB
  __shared__ uint32_t w32[8][64][20];         // per-wave [q][col] slices, 40 KB

  const int u = (blockIdx.x & 7) * 64 + (blockIdx.x >> 3);
  const int quarter = u & 3, h = (u >> 2) & 15, s = (u >> 6) & 3, b = u >> 8;
  const int tid = threadIdx.x, w = tid >> 6, lane = tid & 63;
  const int lr = lane & 15, lq = lane >> 4;
  const long qrow0 = (long)b * 8192 + s * 2048 + quarter * 512 + w * 64;
  const int hc = h * 64;

  const unsigned short* kbase = kb + ((long)(b * 4 + s) * 256) * 1024 + hc;
  const unsigned short* vbase = vtb + ((long)(b * 4 + s) * 1024 + hc) * 256;

#pragma unroll
  for (int it = 0; it < 4; ++it) {
    int e = (it * 512 + tid) * 8;
    int f = e >> 8;
    int ch = (e >> 3) & 31;
    gload_lds16(vbase + (long)f * 256 + ((ch ^ (f & 7)) * 8), &v_t[e]);
  }

  const unsigned short* qbase = qb + qrow0 * 1024 + hc;
  short8 aq[4][2];
#pragma unroll
  for (int i = 0; i < 4; ++i)
#pragma unroll
    for (int kk = 0; kk < 2; ++kk)
      aq[i][kk] = *(const short8*)&qbase[(i * 16 + lr) * 1024 + (kk * 4 + lq) * 8];

  __syncthreads();   // V staged (only barrier in the kernel)

  short8 ones;
#pragma unroll
  for (int e = 0; e < 8; ++e) ones[e] = (short)0x3F80;  // bf16 1.0

  uint32_t (*wsl)[20] = w32[w];

  f32x4 acc_pv[4][4] = {};
  f32x4 acc_den[4] = {};
  short8 bk0[2][2], bk1[2][2];
  f32x4 sA[4][2], sB[4][2];

#define LOADK(BK, CC) do { \
  _Pragma("unroll") for (int j = 0; j < 2; ++j) \
    _Pragma("unroll") for (int kk = 0; kk < 2; ++kk) \
      BK[j][kk] = *(const short8*)&kbase[(long)((CC) * 32 + j * 16 + lr) * 1024 + (kk * 4 + lq) * 8]; \
} while (0)

#define QKT(S, BK) do { \
  _Pragma("unroll") for (int i = 0; i < 4; ++i) \
    _Pragma("unroll") for (int j = 0; j < 2; ++j) { \
      f32x4 z = {0.f, 0.f, 0.f, 0.f}; S[i][j] = z; } \
  _Pragma("unroll") for (int kk = 0; kk < 2; ++kk) \
    _Pragma("unroll") for (int i = 0; i < 4; ++i) \
      _Pragma("unroll") for (int j = 0; j < 2; ++j) \
        S[i][j] = __builtin_amdgcn_mfma_f32_16x16x32_bf16(aq[i][kk], BK[j][kk], S[i][j], 0, 0, 0); \
} while (0)

#define SOFTPV(S, CC) do { \
  float c0 = -3.4e38f, c1 = -3.4e38f; \
  _Pragma("unroll") for (int i = 0; i < 4; ++i) \
    _Pragma("unroll") for (int r = 0; r < 4; ++r) { \
      c0 = fmaxf(c0, S[i][0][r]); c1 = fmaxf(c1, S[i][1][r]); } \
  c0 = fmaxf(c0, __shfl_xor(c0, 16)); c0 = fmaxf(c0, __shfl_xor(c0, 32)); \
  c1 = fmaxf(c1, __shfl_xor(c1, 16)); c1 = fmaxf(c1, __shfl_xor(c1, 32)); \
  _Pragma("unroll") for (int i = 0; i < 4; ++i) \
    _Pragma("unroll") for (int r = 0; r < 4; ++r) { \
      int qq = i * 16 + lq * 4 + r; \
      wsl[qq][lr] = pack_bf16(__expf(S[i][0][r] - c0), __expf(S[i][1][r] - c1)); } \
  short8 av_[4]; \
  _Pragma("unroll") for (int ct = 0; ct < 4; ++ct) { \
    int frow = ct * 16 + lr; \
    av_[ct] = *(const short8*)&v_t[frow * 256 + ((((CC) * 4 + lq) ^ (frow & 7)) << 3)]; } \
  _Pragma("unroll") for (int qi = 0; qi < 4; ++qi) { \
    short8 bw = *(const short8*)&wsl[qi * 16 + lr][lq * 4]; \
    acc_den[qi] = __builtin_amdgcn_mfma_f32_16x16x32_bf16(ones, bw, acc_den[qi], 0, 0, 0); \
    _Pragma("unroll") for (int ct = 0; ct < 4; ++ct) \
      acc_pv[qi][ct] = __builtin_amdgcn_mfma_f32_16x16x32_bf16(av_[ct], bw, acc_pv[qi][ct], 0, 0, 0); } \
} while (0)

  // prologue: K chunks 0,1 in regs; scores for chunk 0
  LOADK(bk0, 0);
  LOADK(bk1, 1);
  QKT(sA, bk0);

  // 2-deep pipeline, unrolled (named banks; no runtime indexing)
  LOADK(bk0, 2); QKT(sB, bk1); SOFTPV(sA, 0);
  LOADK(bk1, 3); QKT(sA, bk0); SOFTPV(sB, 1);
  LOADK(bk0, 4); QKT(sB, bk1); SOFTPV(sA, 2);
  LOADK(bk1, 5); QKT(sA, bk0); SOFTPV(sB, 3);
  LOADK(bk0, 6); QKT(sB, bk1); SOFTPV(sA, 4);
  LOADK(bk1, 7); QKT(sA, bk0); SOFTPV(sB, 5);
                 QKT(sB, bk1); SOFTPV(sA, 6);
                               SOFTPV(sB, 7);

  // ---- epilogue: out[q][f] = num/den, packed 8B stores
#pragma unroll
  for (int qi = 0; qi < 4; ++qi) {
    float inv = 1.0f / (acc_den[qi][0] + 1e-10f);
    long orow = (qrow0 + qi * 16 + lr) * 1024 + hc;
#pragma unroll
    for (int ct = 0; ct < 4; ++ct) {
      ushort4v p;
#pragma unroll
      for (int r = 0; r < 4; ++r) p[r] = f2bf(acc_pv[qi][ct][r] * inv);
      *(ushort4v*)&attout[orow + ct * 16 + lq * 4] = p;
    }
  }
}

extern "C" void kernel_launch(void* const* d_in, const int* in_sizes, int n_in,
                              void* d_out, int out_size, void* d_ws, size_t ws_size,
                              hipStream_t stream) {
  (void)in_sizes; (void)n_in; (void)out_size; (void)ws_size;
  const float* x    = (const float*)d_in[0];
  const float* Wqkv = (const float*)d_in[1];
  const float* Wout = (const float*)d_in[2];
  float* out = (float*)d_out;
  char* ws = (char*)d_ws;

  // workspace layout (80 MB). xb aliases attout: xb is dead before attn writes.
  unsigned short* xb     = (unsigned short*)(ws);               // 33,554,432 B
  unsigned short* attout = (unsigned short*)(ws);               // (same region)
  unsigned short* wqkvb  = (unsigned short*)(ws + 33554432);    //  6,291,456 B
  unsigned short* woutb  = (unsigned short*)(ws + 39845888);    //  2,097,152 B
  unsigned short* qbuf   = (unsigned short*)(ws + 41943040);    // 33,554,432 B
  unsigned short* kbuf   = (unsigned short*)(ws + 75497472);    //  4,194,304 B
  unsigned short* vtb    = (unsigned short*)(ws + 79691776);    //  4,194,304 B

  cvt_kernel<<<16384, 256, 0, stream>>>(x, xb, 16777216);
  cvt_kernel<<<3072, 256, 0, stream>>>(Wqkv, wqkvb, 3 * 1024 * 1024);
  cvt_kernel<<<1024, 256, 0, stream>>>(Wout, woutb, 1024 * 1024);

  // Q = (x @ Wq^T) * hd^-0.5  -> qbuf (8-phase 256^2)
  gemm8p<false><<<dim3(64, 4), 512, 0, stream>>>(xb, wqkvb, (void*)qbuf, 0.125f);
  // K,V at dilated rows (every 8th): K -> kbuf [2048][1024], V -> vtb (sigma V^T)
  gemm_bt<2><<<dim3(16, 16), 256, 0, stream>>>(
      xb, wqkvb + 1024 * 1024, (void*)kbuf, vtb, 1.0f, 8192, 1024, 1024);

  attn_kernel<<<512, 512, 0, stream>>>(qbuf, kbuf, vtb, attout);

  // final projection: out = attout @ Wout^T (f32 output, 8-phase 256^2)
  gemm8p<true><<<dim3(64, 4), 512, 0, stream>>>(attout, woutb, (void*)out, 1.0f);
}